// Round 11
// baseline (119.531 us; speedup 1.0000x reference)
//
#include <hip/hip_runtime.h>
#include <math.h>

#define T_  1024
#define H_  1024
#define DK_ 512
#define DV_ 1024
#define LR_ 16
#define CHUNK 64
#define PN  3200   // fused projection width: q(512)|k(512)|v(1024)|g(1024)|xg1pad(128)

using f32x4  = __attribute__((ext_vector_type(4))) float;
using f32x16 = __attribute__((ext_vector_type(16))) float;
using bf16x8 = __attribute__((ext_vector_type(8))) short;
using u16x4  = __attribute__((ext_vector_type(4))) unsigned short;
typedef unsigned short u16;

__device__ __forceinline__ u16 f2bf(float f) {
  union { float f; unsigned int u; } v; v.f = f;
  unsigned int r = v.u + 0x7FFF + ((v.u >> 16) & 1);
  return (u16)(r >> 16);
}
__device__ __forceinline__ float bf2f(u16 u) {
  union { unsigned int i; float f; } v; v.i = ((unsigned int)u) << 16;
  return v.f;
}
__device__ __forceinline__ void gll16(const void* g, void* l) {
  __builtin_amdgcn_global_load_lds((const __attribute__((address_space(1))) void*)g,
                                   (__attribute__((address_space(3))) void*)l, 16, 0, 0);
}

// ---------------------------------------------------------------------------
// 128x128-tile bf16 GEMM via mfma_f32_32x32x16. A: LDS double-buffered via
// global_load_lds. B: DIRECT per-wave global reads (L2-served panels; lesson
// #7 — don't stage what cache fits). 1-D grid, n-major XCD-chunk swizzle.
// VT: blocks in the V column range also emit the transposed tile to Vtb.
// ---------------------------------------------------------------------------
template <bool OBF, bool VT>
__global__ __launch_bounds__(256) void gemm128(const u16* __restrict__ A,
                                               const u16* __restrict__ Bt,
                                               void* __restrict__ Cv,
                                               u16* __restrict__ Vtb,
                                               int M, int N, int K,
                                               int ntile_m, int chunk) {
  __shared__ u16 Asm[2][8192];   // 2 x (128 x 64)
  int tid = threadIdx.x, w = tid >> 6, l = tid & 63;
  int bid = blockIdx.x;
  int swz = (bid & 7) * chunk + (bid >> 3);
  int nt = swz / ntile_m, mt = swz - nt * ntile_m;
  int bm = mt << 7, bn = nt << 7;

  int srow = (w << 3) + (l >> 3);
  int schunk = ((l & 7) ^ (l >> 3)) << 3;
  const u16* pA = A + (size_t)(bm + srow) * K + schunk;
  char* AsmB = (char*)Asm;
  int ldsw = w << 10;

  int wr = w >> 1, wc = w & 1;
  int l31 = l & 31, hi = l >> 5;
  // direct-global B row pointers for this wave (rows bn + wc*64 + mi*32 + l31)
  const u16* pB0 = Bt + (size_t)(bn + wc * 64 + l31) * K + (hi << 3);
  const u16* pB1 = pB0 + (size_t)32 * K;

  int nt_k = K >> 6;
#pragma unroll
  for (int i = 0; i < 4; ++i)
    gll16(pA + (size_t)(i * 32) * K, AsmB + i * 4096 + ldsw);
  __syncthreads();

  f32x16 acc[2][2] = {};
  int cur = 0;
  for (int t = 0; t < nt_k; ++t) {
    int k0 = t << 6;
    if (t + 1 < nt_k) {           // prefetch next A tile into other buffer
      int off = (cur ^ 1) << 14;
#pragma unroll
      for (int i = 0; i < 4; ++i)
        gll16(pA + (size_t)(i * 32) * K + k0 + 64, AsmB + off + i * 4096 + ldsw);
    }
    // B fragments: direct global (16B per lane, L2-hit)
    bf16x8 b[2][4];
#pragma unroll
    for (int ks = 0; ks < 4; ++ks) {
      b[0][ks] = *(const bf16x8*)(pB0 + k0 + (ks << 4));
      b[1][ks] = *(const bf16x8*)(pB1 + k0 + (ks << 4));
    }
    const u16* Ac = Asm[cur];
    bf16x8 a[2][4];
#pragma unroll
    for (int mi = 0; mi < 2; ++mi)
#pragma unroll
      for (int ks = 0; ks < 4; ++ks) {
        int ar = wr * 64 + mi * 32 + l31;
        a[mi][ks] = *(const bf16x8*)(Ac + ar * 64 + ((((ks << 1) + hi) ^ (ar & 7)) << 3));
      }
#pragma unroll
    for (int ks = 0; ks < 4; ++ks)
#pragma unroll
      for (int mi = 0; mi < 2; ++mi)
#pragma unroll
        for (int ni = 0; ni < 2; ++ni)
          acc[mi][ni] = __builtin_amdgcn_mfma_f32_32x32x16_bf16(
              a[mi][ks], b[ni][ks], acc[mi][ni], 0, 0, 0);
    __syncthreads();
    cur ^= 1;
  }
  // C/D: col = l&31, row = (reg&3) + 8*(reg>>2) + 4*(l>>5)
#pragma unroll
  for (int mi = 0; mi < 2; ++mi)
#pragma unroll
    for (int ni = 0; ni < 2; ++ni) {
      int colg = bn + wc * 64 + ni * 32 + l31;
#pragma unroll
      for (int q = 0; q < 4; ++q) {
        int row0 = bm + wr * 64 + mi * 32 + q * 8 + hi * 4;
#pragma unroll
        for (int j = 0; j < 4; ++j) {
          float vv = acc[mi][ni][q * 4 + j];
          if (OBF) ((u16*)Cv)[(size_t)(row0 + j) * N + colg] = f2bf(vv);
          else     ((float*)Cv)[(size_t)(row0 + j) * N + colg] = vv;
        }
      }
    }
  if (VT && bn >= 1024 && bn < 2048) {   // also emit V^T for this tile
    int h = (bn - 1024) >> 8;
    int bb_ = bm >> 10;
    u16* vt = Vtb + (size_t)(bb_ * 4 + h) * 262144;
    int tbase = bm & 1023;
#pragma unroll
    for (int mi = 0; mi < 2; ++mi)
#pragma unroll
      for (int ni = 0; ni < 2; ++ni) {
        int vcl = ((bn - 1024) & 255) + wc * 64 + ni * 32 + l31;
#pragma unroll
        for (int q = 0; q < 4; ++q) {
          int t0 = tbase + wr * 64 + mi * 32 + q * 8 + hi * 4;
          u16x4 o = {f2bf(acc[mi][ni][q * 4 + 0]), f2bf(acc[mi][ni][q * 4 + 1]),
                     f2bf(acc[mi][ni][q * 4 + 2]), f2bf(acc[mi][ni][q * 4 + 3])};
          *(u16x4*)&vt[(size_t)vcl * 1024 + t0] = o;
        }
      }
  }
}

// ---------------------------------------------------------------------------
// 128x64-tile bf16 GEMM (final Wo). A: LDS dbuf; B: direct global (2 MB weight,
// L2/L3-served). Grid 1-D (256), m-major XCD chunks.
// ---------------------------------------------------------------------------
__global__ __launch_bounds__(256) void gemmWo(const u16* __restrict__ A,
                                              const u16* __restrict__ Bt,
                                              float* __restrict__ C,
                                              int M, int N, int K) {
  __shared__ u16 Asm[2][8192];   // 2 x (128 x 64)
  int tid = threadIdx.x, w = tid >> 6, l = tid & 63;
  int bid = blockIdx.x;
  int swz = (bid & 7) * 32 + (bid >> 3);   // 256 % 8 == 0 -> bijective
  int mt = swz >> 4, ntile = swz & 15;     // m-major: 16 n-tiles per m
  int bm = mt << 7, bn = ntile << 6;

  int srow = (w << 3) + (l >> 3);
  int schunk = ((l & 7) ^ (l >> 3)) << 3;
  const u16* pA = A + (size_t)(bm + srow) * K + schunk;
  char* AsmB = (char*)Asm;
  int ldsw = w << 10;
  int l31 = l & 31, hi = l >> 5;
  const u16* pB0 = Bt + (size_t)(bn + l31) * K + (hi << 3);
  const u16* pB1 = pB0 + (size_t)32 * K;

  int nt = K >> 6;
#pragma unroll
  for (int i = 0; i < 4; ++i)
    gll16(pA + (size_t)(i * 32) * K, AsmB + i * 4096 + ldsw);
  __syncthreads();

  f32x16 acc[2] = {};
  int cur = 0;
  for (int t = 0; t < nt; ++t) {
    int k0 = t << 6;
    if (t + 1 < nt) {
#pragma unroll
      for (int i = 0; i < 4; ++i)
        gll16(pA + (size_t)(i * 32) * K + k0 + 64, AsmB + ((cur ^ 1) << 14) + i * 4096 + ldsw);
    }
    bf16x8 b[2][4];
#pragma unroll
    for (int ks = 0; ks < 4; ++ks) {
      b[0][ks] = *(const bf16x8*)(pB0 + k0 + (ks << 4));
      b[1][ks] = *(const bf16x8*)(pB1 + k0 + (ks << 4));
    }
    const u16* Ac = Asm[cur];
    bf16x8 a[4];
#pragma unroll
    for (int ks = 0; ks < 4; ++ks) {
      int ar = w * 32 + l31;
      a[ks] = *(const bf16x8*)(Ac + ar * 64 + ((((ks << 1) + hi) ^ (ar & 7)) << 3));
    }
#pragma unroll
    for (int ks = 0; ks < 4; ++ks)
#pragma unroll
      for (int ni = 0; ni < 2; ++ni)
        acc[ni] = __builtin_amdgcn_mfma_f32_32x32x16_bf16(a[ks], b[ni][ks], acc[ni], 0, 0, 0);
    __syncthreads();
    cur ^= 1;
  }
#pragma unroll
  for (int ni = 0; ni < 2; ++ni) {
    int colg = bn + ni * 32 + l31;
#pragma unroll
    for (int q = 0; q < 4; ++q) {
      int row0 = bm + w * 32 + q * 8 + hi * 4;
#pragma unroll
      for (int j = 0; j < 4; ++j)
        C[(size_t)(row0 + j) * N + colg] = acc[ni][q * 4 + j];
    }
  }
}

// ---------------------------------------------------------------------------
// Fused misc prep: z=0..3 weight transposes into fused WallTb, z=4 Wo->Wotb,
// z=5 x->bf16, z=6 Wgk1^T zero-padded into WallTb rows 3072..3199.
// ---------------------------------------------------------------------------
__global__ __launch_bounds__(256) void prep_misc(const float* __restrict__ x,
                                                 const float* __restrict__ Wq,
                                                 const float* __restrict__ Wk,
                                                 const float* __restrict__ Wv,
                                                 const float* __restrict__ Wg,
                                                 const float* __restrict__ Wo,
                                                 const float* __restrict__ Wgk1,
                                                 u16* __restrict__ xbb,
                                                 u16* __restrict__ WallTb,
                                                 u16* __restrict__ Wotb) {
  int z = blockIdx.z;
  int tid = threadIdx.x;
  if (z == 5) {
    size_t i0 = ((size_t)(blockIdx.y * 32 + blockIdx.x)) * 2048 + tid * 4;
    float4 v0 = *(const float4*)&x[i0];
    float4 v1 = *(const float4*)&x[i0 + 1024];
    u16x4 o0 = {f2bf(v0.x), f2bf(v0.y), f2bf(v0.z), f2bf(v0.w)};
    u16x4 o1 = {f2bf(v1.x), f2bf(v1.y), f2bf(v1.z), f2bf(v1.w)};
    *(u16x4*)&xbb[i0] = o0;
    *(u16x4*)&xbb[i0 + 1024] = o1;
    return;
  }
  if (z == 6) {
    if (blockIdx.x != 0) return;
    int col = blockIdx.y * 32 + (tid & 31);
#pragma unroll
    for (int i = 0; i < 16; ++i) {
      int rr = (tid >> 5) + i * 8;   // 0..127
      float v = (rr < LR_) ? Wgk1[(size_t)col * LR_ + rr] : 0.f;
      WallTb[(size_t)(3072 + rr) * 1024 + col] = f2bf(v);
    }
    return;
  }
  const float* in; u16* outp; int C;
  if (z == 0)      { in = Wq; outp = WallTb;               C = 512; }
  else if (z == 1) { in = Wk; outp = WallTb + 512 * 1024;  C = 512; }
  else if (z == 2) { in = Wv; outp = WallTb + 1024 * 1024; C = 1024; }
  else if (z == 3) { in = Wg; outp = WallTb + 2048 * 1024; C = 1024; }
  else             { in = Wo; outp = Wotb;                 C = 1024; }
  int bx = blockIdx.x << 5, by = blockIdx.y << 5;
  if (bx >= C) return;
  __shared__ float tile[32][33];
  int tx = tid & 31, ty = tid >> 5;
#pragma unroll
  for (int i = 0; i < 32; i += 8)
    tile[ty + i][tx] = in[(size_t)(by + ty + i) * C + bx + tx];
  __syncthreads();
#pragma unroll
  for (int i = 0; i < 32; i += 8)
    outp[(size_t)(bx + ty + i) * 1024 + by + tx] = f2bf(tile[tx][ty + i]);
}

// ---------------------------------------------------------------------------
// prep2: gate (xg1@Wgk2+b -> logsigmoid/16 -> prefix), bf16 Q~/Kinv/KdecT, D.
// grid 256 = (unit 0..127) x (j-half jh). Each block owns 64 gate columns.
// ---------------------------------------------------------------------------
__global__ __launch_bounds__(256) void prep2(const float* __restrict__ Wgk2,
                                             const float* __restrict__ bgk2,
                                             const u16* __restrict__ Pb,
                                             u16* __restrict__ qtb,
                                             u16* __restrict__ kinvb,
                                             u16* __restrict__ kdecTb,
                                             float* __restrict__ D) {
  __shared__ float gc[64][65];
  __shared__ u16 kbuf[64][65];
  __shared__ float xs[64][17];
  int bx = blockIdx.x;
  int unit = bx >> 1, jh = bx & 1;
  int c = unit & 15, bh = unit >> 4;
  int b = bh >> 2, h = bh & 3;
  int tid = threadIdx.x;
  int brow = b * T_ + c * CHUNK;
  size_t gbase = (size_t)brow * 512 + h * 128 + jh * 64;

#pragma unroll
  for (int e = 0; e < 4; ++e) {
    int idx = e * 256 + tid;
    int i = idx >> 4, r = idx & 15;
    xs[i][r] = bf2f(Pb[(size_t)(brow + i) * PN + 3072 + r]);
  }
  __syncthreads();
  {
    int j = tid & 63, i0 = tid >> 6;
    int n = h * 128 + jh * 64 + j;
    float w2[LR_];
#pragma unroll
    for (int r = 0; r < LR_; ++r) w2[r] = Wgk2[r * DK_ + n];
    float bb = bgk2[n];
#pragma unroll 4
    for (int e = 0; e < 16; ++e) {
      int i = e * 4 + i0;
      float sv = bb;
#pragma unroll
      for (int r = 0; r < LR_; ++r) sv = fmaf(xs[i][r], w2[r], sv);
      float ls = fminf(sv, 0.f) - log1pf(__expf(-fabsf(sv)));
      gc[i][j] = ls * (1.0f / 16.0f);
    }
  }
  __syncthreads();
  if (tid < 64) {
    float g = 0.f;
    for (int i = 0; i < 64; ++i) { g += gc[i][tid]; gc[i][tid] = g; }
    D[unit * 128 + jh * 64 + tid] = __expf(g);
  }
  __syncthreads();

  const float scale = 0.08838834764831845f;
  const u16* Pq = Pb + (size_t)brow * PN + h * 128 + jh * 64;
  const u16* Pk = Pq + 512;
#pragma unroll 4
  for (int e = 0; e < 16; ++e) {
    int idx = e * 256 + tid;
    int i = idx >> 6, j = idx & 63;
    float gv = gc[i][j];
    u16 ku = Pk[(size_t)i * PN + j];
    kbuf[i][j] = ku;
    float qv = bf2f(Pq[(size_t)i * PN + j]);
    float kv = bf2f(ku);
    qtb[gbase + (size_t)i * 512 + j]   = f2bf(qv * __expf(gv) * scale);
    kinvb[gbase + (size_t)i * 512 + j] = f2bf(kv * __expf(-gv));
  }
  __syncthreads();
  u16* kd = kdecTb + (size_t)unit * 8192 + (size_t)(jh * 64) * 64;
#pragma unroll 4
  for (int e = 0; e < 16; ++e) {
    int idx = e * 256 + tid;
    int j = idx >> 6, i = idx & 63;
    float kv = bf2f(kbuf[i][j]);
    float gv = gc[i][j];
    float G  = gc[63][j];
    kd[(size_t)j * 64 + i] = f2bf(kv * __expf(G - gv));
  }
}

// ---------------------------------------------------------------------------
// state_combine: per (kh, vs, bh) block, V^T slice resident in LDS; for each
// chunk c: U = KdecT@V (MFMA, KdecT double-buffered), S = D*S + U in regs,
// StT[c+1] written bf16. Slot 0 zeroed. grid (2, 16, 8).
// ---------------------------------------------------------------------------
__global__ __launch_bounds__(256) void state_combine(const u16* __restrict__ Vtb,
                                                     const u16* __restrict__ kdecTb,
                                                     const float* __restrict__ D,
                                                     u16* __restrict__ StT) {
  __shared__ u16 VtS[16384];    // 16 v-rows x 1024 t (chunk-swizzled)
  __shared__ u16 Kdb[2][4096];  // 64 k-rows x 64 t, double-buffered
  int kh = blockIdx.x, vs = blockIdx.y, bh = blockIdx.z;
  int tid = threadIdx.x, w = tid >> 6, l = tid & 63;
  int lrow = l & 15, g4 = l >> 4;
  int unit0 = bh * 16;

  {
    const u16* base = Vtb + (size_t)bh * 262144 + (size_t)(vs * 16) * 1024;
#pragma unroll
    for (int i = 0; i < 8; ++i) {
      int slin = i * 256 + w * 64 + l;
      int row = slin >> 7, chd = slin & 127;
      gll16(base + (size_t)row * 1024 + ((chd ^ (row & 7)) << 3),
            (char*)VtS + i * 4096 + (w << 10));
    }
  }
  int vc = vs * 16 + lrow;
  int kd0 = kh * 64 + w * 16 + (g4 << 2);
  {
    u16x4 z = {0, 0, 0, 0};
    *(u16x4*)&StT[(size_t)bh * 32768 + (size_t)vc * 128 + kd0] = z;
  }
  {
    const u16* kb = kdecTb + (size_t)unit0 * 8192 + (size_t)(kh * 64) * 64;
#pragma unroll
    for (int i = 0; i < 2; ++i) {
      int slin = i * 256 + w * 64 + l;
      int row = slin >> 3, chd = slin & 7;
      gll16(kb + (size_t)row * 64 + ((chd ^ (row & 7)) << 3),
            (char*)Kdb[0] + i * 4096 + (w << 10));
    }
  }
  f32x4 S = {};
  int cur = 0;
  for (int c = 0; c < 15; ++c) {
    __syncthreads();
    if (c < 14) {
      const u16* kb = kdecTb + (size_t)(unit0 + c + 1) * 8192 + (size_t)(kh * 64) * 64;
#pragma unroll
      for (int i = 0; i < 2; ++i) {
        int slin = i * 256 + w * 64 + l;
        int row = slin >> 3, chd = slin & 7;
        gll16(kb + (size_t)row * 64 + ((chd ^ (row & 7)) << 3),
              (char*)Kdb[cur ^ 1] + i * 4096 + (w << 10));
      }
    }
    const u16* Kc = Kdb[cur];
    f32x4 acc = {};
#pragma unroll
    for (int ks = 0; ks < 2; ++ks) {
      int cidx = c * 8 + ks * 4 + g4;
      bf16x8 bv = *(const bf16x8*)(VtS + lrow * 1024 + ((cidx ^ (lrow & 7)) << 3));
      int row = w * 16 + lrow;
      bf16x8 av = *(const bf16x8*)(Kc + row * 64 + ((((ks << 2) + g4) ^ (row & 7)) << 3));
      acc = __builtin_amdgcn_mfma_f32_16x16x32_bf16(av, bv, acc, 0, 0, 0);
    }
    float4 dv = *(const float4*)&D[(size_t)(unit0 + c) * 128 + kd0];
    S[0] = fmaf(dv.x, S[0], acc[0]);
    S[1] = fmaf(dv.y, S[1], acc[1]);
    S[2] = fmaf(dv.z, S[2], acc[2]);
    S[3] = fmaf(dv.w, S[3], acc[3]);
    u16x4 o = {f2bf(S[0]), f2bf(S[1]), f2bf(S[2]), f2bf(S[3])};
    *(u16x4*)&StT[((size_t)(c + 1) * 8 + bh) * 32768 + (size_t)vc * 128 + kd0] = o;
    cur ^= 1;
  }
}

// ---------------------------------------------------------------------------
// Fused per-half-unit: A = mask(Q~ Kinv^T); O = A V + Q~ S; RMSNorm*gw*swish.
// grid 256 = (unit) x (row-half s). 32 rows x 256 v-cols per block.
// ---------------------------------------------------------------------------
__global__ __launch_bounds__(256) void fused_out(const u16* __restrict__ qtb,
                                                 const u16* __restrict__ kinvb,
                                                 const u16* __restrict__ Vtb,
                                                 const u16* __restrict__ StTb,
                                                 const u16* __restrict__ Pb,
                                                 const float* __restrict__ gw,
                                                 u16* __restrict__ onb) {
  __shared__ u16 Qs[4096];
  __shared__ u16 As[2048];
  __shared__ float rsum[32][4];
  int bx = blockIdx.x;
  int unit = bx >> 1, s = bx & 1;
  int c = unit & 15, bh = unit >> 4;
  int b = bh >> 2, h = bh & 3;
  int tid = threadIdx.x, w = tid >> 6, l = tid & 63;
  int lrow = l & 15, g4 = l >> 4, lx = l & 7;
  int crow = b * T_ + c * CHUNK;
  int brow = crow + s * 32;

  {
    int r0 = tid >> 4;
    int csrc = ((tid & 15) ^ (r0 & 7)) << 3;
    const u16* src = qtb + (size_t)(brow + r0) * 512 + h * 128 + csrc;
    gll16(src, (char*)Qs + (w << 10));
    gll16(src + 16 * 512, (char*)Qs + 4096 + (w << 10));
  }
  const u16* Kbase = kinvb + (size_t)crow * 512 + h * 128;
  int wc1 = w & 1, fr = w >> 1;
  bf16x8 bk[2][4];
#pragma unroll
  for (int nj = 0; nj < 2; ++nj)
#pragma unroll
    for (int ks = 0; ks < 4; ++ks)
      bk[nj][ks] = *(const bf16x8*)(Kbase + (size_t)(wc1 * 32 + nj * 16 + lrow) * 512 + ks * 32 + (g4 << 3));
  __syncthreads();

  f32x4 accA[2] = {};
#pragma unroll
  for (int ks = 0; ks < 4; ++ks) {
    int arow = fr * 16 + lrow;
    bf16x8 aq = *(const bf16x8*)(Qs + arow * 128 + ((((ks << 2) + g4) ^ lx) << 3));
#pragma unroll
    for (int nj = 0; nj < 2; ++nj)
      accA[nj] = __builtin_amdgcn_mfma_f32_16x16x32_bf16(aq, bk[nj][ks], accA[nj], 0, 0, 0);
  }
#pragma unroll
  for (int nj = 0; nj < 2; ++nj)
#pragma unroll
    for (int j = 0; j < 4; ++j) {
      int rg = fr * 16 + (g4 << 2) + j;
      int col = wc1 * 32 + nj * 16 + lrow;
      float vv = (col <= s * 32 + rg) ? accA[nj][j] : 0.f;
      int chunk = (col >> 3) ^ (rg & 7);
      As[rg * 64 + (chunk << 3) + (lrow & 7)] = f2bf(vv);
    }
  __syncthreads();

  f32x4 acc[2][4] = {};
  const u16* Vbase = Vtb + (size_t)bh * 262144 + (size_t)(w * 64) * 1024 + c * 64;
  const u16* Sbase = StTb + (((size_t)(c * 8 + bh)) * 256 + w * 64) * 128;
#pragma unroll
  for (int ks2 = 0; ks2 < 2; ++ks2) {
    bf16x8 bv[4];
#pragma unroll
    for (int nj = 0; nj < 4; ++nj)
      bv[nj] = *(const bf16x8*)(Vbase + (size_t)(nj * 16 + lrow) * 1024 + ks2 * 32 + (g4 << 3));
#pragma unroll
    for (int mi = 0; mi < 2; ++mi) {
      int row = mi * 16 + lrow;
      bf16x8 aa = *(const bf16x8*)(As + row * 64 + ((((ks2 << 2) + g4) ^ lx) << 3));
#pragma unroll
      for (int nj = 0; nj < 4; ++nj)
        acc[mi][nj] = __builtin_amdgcn_mfma_f32_16x16x32_bf16(aa, bv[nj], acc[mi][nj], 0, 0, 0);
    }
  }
#pragma unroll
  for (int ks = 0; ks < 4; ++ks) {
    bf16x8 bs[4];
#pragma unroll
    for (int nj = 0; nj < 4; ++nj)
      bs[nj] = *(const bf16x8*)(Sbase + (size_t)(nj * 16 + lrow) * 128 + ks * 32 + (g4 << 3));
#pragma unroll
    for (int mi = 0; mi < 2; ++mi) {
      int row = mi * 16 + lrow;
      bf16x8 aq = *(const bf16x8*)(Qs + row * 128 + ((((ks << 2) + g4) ^ lx) << 3));
#pragma unroll
      for (int nj = 0; nj < 4; ++nj)
        acc[mi][nj] = __builtin_amdgcn_mfma_f32_16x16x32_bf16(aq, bs[nj], acc[mi][nj], 0, 0, 0);
    }
  }

#pragma unroll
  for (int mi = 0; mi < 2; ++mi)
#pragma unroll
    for (int j = 0; j < 4; ++j) {
      float ss = 0.f;
#pragma unroll
      for (int nj = 0; nj < 4; ++nj) { float o = acc[mi][nj][j]; ss = fmaf(o, o, ss); }
      ss += __shfl_xor(ss, 1);
      ss += __shfl_xor(ss, 2);
      ss += __shfl_xor(ss, 4);
      ss += __shfl_xor(ss, 8);
      if (lrow == 0) rsum[mi * 16 + (g4 << 2) + j][w] = ss;
    }
  __syncthreads();
  const u16* Gbase = Pb + (size_t)brow * PN + 2048 + h * 256;
#pragma unroll
  for (int mi = 0; mi < 2; ++mi)
#pragma unroll
    for (int j = 0; j < 4; ++j) {
      int row = mi * 16 + (g4 << 2) + j;
      float4 rs = *(float4*)&rsum[row][0];
      float rn = rsqrtf((rs.x + rs.y + rs.z + rs.w) * (1.f / 256.f) + 1e-5f);
#pragma unroll
      for (int nj = 0; nj < 4; ++nj) {
        int vc = w * 64 + nj * 16 + lrow;
        float o = acc[mi][nj][j] * rn * gw[vc];
        float gval = bf2f(Gbase[(size_t)row * PN + vc]);
        float sw = gval / (1.f + __expf(-gval));
        onb[(size_t)(brow + row) * 1024 + h * 256 + vc] = f2bf(o * sw);
      }
    }
}

// ---------------------------------------------------------------------------
extern "C" void kernel_launch(void* const* d_in, const int* in_sizes, int n_in,
                              void* d_out, int out_size, void* d_ws, size_t ws_size,
                              hipStream_t stream) {
  const float* x    = (const float*)d_in[0];
  const float* Wq   = (const float*)d_in[1];
  const float* Wk   = (const float*)d_in[2];
  const float* Wv   = (const float*)d_in[3];
  const float* Wgk1 = (const float*)d_in[4];
  const float* Wgk2 = (const float*)d_in[5];
  const float* bgk2 = (const float*)d_in[6];
  const float* Wg   = (const float*)d_in[7];
  const float* Wo   = (const float*)d_in[8];
  const float* gw   = (const float*)d_in[9];
  float* out = (float*)d_out;

  float* F = (float*)d_ws;
  u16*   Pb     = (u16*)F;                       // [2048][3200] bf16
  u16*   WallTb = (u16*)(F + 3276800);           // [3200][1024] bf16 -> kdecT+onb
  u16*   Wotb   = (u16*)(F + 4915200);           // [1024][1024] bf16
  u16*   xbb    = (u16*)(F + 5439488);           // x bf16 -> qtb+kinvb
  u16*   Vtb    = (u16*)(F + 6488064);           // [8][256][1024] bf16
  float* D      = F + 7536640;                   // [128][128] f32
  u16*   StT    = (u16*)(F + 7553024);           // [16][8][32768] bf16

  u16* qtb    = xbb;                             // aliases (xbb dead after proj)
  u16* kinvb  = xbb + 1048576;
  u16* kdecTb = WallTb;                          // WallTb dead after proj
  u16* onb    = WallTb + 1048576;

  dim3 blk(256);
  prep_misc<<<dim3(32, 32, 7), blk, 0, stream>>>(x, Wq, Wk, Wv, Wg, Wo, Wgk1,
                                                 xbb, WallTb, Wotb);
  // 400 tiles (25 n x 16 m), n-major, 50 tiles per XCD chunk
  gemm128<true, true><<<dim3(400), blk, 0, stream>>>(xbb, WallTb, Pb, Vtb,
                                                     2048, PN, H_, 16, 50);
  prep2<<<256, blk, 0, stream>>>(Wgk2, bgk2, Pb, qtb, kinvb, kdecTb, D);
  state_combine<<<dim3(2, 16, 8), blk, 0, stream>>>(Vtb, kdecTb, D, StT);
  fused_out<<<256, blk, 0, stream>>>(qtb, kinvb, Vtb, StT, Pb, gw, onb);
  gemmWo<<<dim3(256), blk, 0, stream>>>(onb, Wotb, out, 2048, H_, DV_);
}

// Round 12
// 92.292 us; speedup vs baseline: 1.2951x; 1.2951x over previous
//
#include <hip/hip_runtime.h>
#include <math.h>

#define T_  1024
#define H_  1024
#define DK_ 512
#define DV_ 1024
#define LR_ 16
#define CHUNK 64
#define PN  3200   // fused projection width: q(512)|k(512)|v(1024)|g(1024)|xg1pad(128)

using f32x4  = __attribute__((ext_vector_type(4))) float;
using f32x16 = __attribute__((ext_vector_type(16))) float;
using bf16x8 = __attribute__((ext_vector_type(8))) short;
using u16x4  = __attribute__((ext_vector_type(4))) unsigned short;
typedef unsigned short u16;

__device__ __forceinline__ u16 f2bf(float f) {
  union { float f; unsigned int u; } v; v.f = f;
  unsigned int r = v.u + 0x7FFF + ((v.u >> 16) & 1);
  return (u16)(r >> 16);
}
__device__ __forceinline__ float bf2f(u16 u) {
  union { unsigned int i; float f; } v; v.i = ((unsigned int)u) << 16;
  return v.f;
}
__device__ __forceinline__ void gll16(const void* g, void* l) {
  __builtin_amdgcn_global_load_lds((const __attribute__((address_space(1))) void*)g,
                                   (__attribute__((address_space(3))) void*)l, 16, 0, 0);
}

// ---------------------------------------------------------------------------
// 128x128-tile bf16 GEMM via mfma_f32_32x32x16, 2-phase double-buffered LDS.
// C[M,N] = A[M,K] @ Bt[N,K]. BK=64, 4 waves, wave = 2x2 of 32x32 frags.
// 1-D grid, n-major XCD-chunk swizzle (bijective, grid%8==0).
// VT: blocks in the V column range also emit the transposed tile to Vtb.
// ---------------------------------------------------------------------------
template <bool OBF, bool VT>
__global__ __launch_bounds__(256) void gemm128(const u16* __restrict__ A,
                                               const u16* __restrict__ Bt,
                                               void* __restrict__ Cv,
                                               u16* __restrict__ Vtb,
                                               int M, int N, int K,
                                               int ntile_m, int chunk) {
  __shared__ u16 Asm[2][8192];   // 2 x (128 x 64)
  __shared__ u16 Bsm[2][8192];
  int tid = threadIdx.x, w = tid >> 6, l = tid & 63;
  int bid = blockIdx.x;
  int swz = (bid & 7) * chunk + (bid >> 3);
  int nt = swz / ntile_m, mt = swz - nt * ntile_m;
  int bm = mt << 7, bn = nt << 7;

  int srow = (w << 3) + (l >> 3);
  int schunk = ((l & 7) ^ (l >> 3)) << 3;
  const u16* pA = A  + (size_t)(bm + srow) * K + schunk;
  const u16* pB = Bt + (size_t)(bn + srow) * K + schunk;
  char* AsmB = (char*)Asm;
  char* BsmB = (char*)Bsm;
  int ldsw = w << 10;

  int wr = w >> 1, wc = w & 1;
  int l31 = l & 31, hi = l >> 5;

  int nt_k = K >> 6;
#pragma unroll
  for (int i = 0; i < 4; ++i) {
    gll16(pA + (size_t)(i * 32) * K, AsmB + i * 4096 + ldsw);
    gll16(pB + (size_t)(i * 32) * K, BsmB + i * 4096 + ldsw);
  }
  __syncthreads();

  f32x16 acc[2][2] = {};
  int cur = 0;
  for (int t = 0; t < nt_k; ++t) {
    if (t + 1 < nt_k) {           // issue next-tile loads into the other buffer
      int k0 = (t + 1) << 6;
      int off = (cur ^ 1) << 14;
#pragma unroll
      for (int i = 0; i < 4; ++i) {
        gll16(pA + (size_t)(i * 32) * K + k0, AsmB + off + i * 4096 + ldsw);
        gll16(pB + (size_t)(i * 32) * K + k0, BsmB + off + i * 4096 + ldsw);
      }
    }
    const u16* Ac = Asm[cur];
    const u16* Bc = Bsm[cur];
    bf16x8 a[2][4], b[2][4];
#pragma unroll
    for (int mi = 0; mi < 2; ++mi)
#pragma unroll
      for (int ks = 0; ks < 4; ++ks) {
        int ar = wr * 64 + mi * 32 + l31;
        int br = wc * 64 + mi * 32 + l31;
        a[mi][ks] = *(const bf16x8*)(Ac + ar * 64 + ((((ks << 1) + hi) ^ (ar & 7)) << 3));
        b[mi][ks] = *(const bf16x8*)(Bc + br * 64 + ((((ks << 1) + hi) ^ (br & 7)) << 3));
      }
#pragma unroll
    for (int ks = 0; ks < 4; ++ks)
#pragma unroll
      for (int mi = 0; mi < 2; ++mi)
#pragma unroll
        for (int ni = 0; ni < 2; ++ni)
          acc[mi][ni] = __builtin_amdgcn_mfma_f32_32x32x16_bf16(
              a[mi][ks], b[ni][ks], acc[mi][ni], 0, 0, 0);
    __syncthreads();
    cur ^= 1;
  }
  // C/D: col = l&31, row = (reg&3) + 8*(reg>>2) + 4*(l>>5)
#pragma unroll
  for (int mi = 0; mi < 2; ++mi)
#pragma unroll
    for (int ni = 0; ni < 2; ++ni) {
      int colg = bn + wc * 64 + ni * 32 + l31;
#pragma unroll
      for (int q = 0; q < 4; ++q) {
        int row0 = bm + wr * 64 + mi * 32 + q * 8 + hi * 4;
#pragma unroll
        for (int j = 0; j < 4; ++j) {
          float vv = acc[mi][ni][q * 4 + j];
          if (OBF) ((u16*)Cv)[(size_t)(row0 + j) * N + colg] = f2bf(vv);
          else     ((float*)Cv)[(size_t)(row0 + j) * N + colg] = vv;
        }
      }
    }
  if (VT && bn >= 1024 && bn < 2048) {   // also emit V^T for this tile
    int h = (bn - 1024) >> 8;
    int bb_ = bm >> 10;
    u16* vt = Vtb + (size_t)(bb_ * 4 + h) * 262144;
    int tbase = bm & 1023;
#pragma unroll
    for (int mi = 0; mi < 2; ++mi)
#pragma unroll
      for (int ni = 0; ni < 2; ++ni) {
        int vcl = ((bn - 1024) & 255) + wc * 64 + ni * 32 + l31;
#pragma unroll
        for (int q = 0; q < 4; ++q) {
          int t0 = tbase + wr * 64 + mi * 32 + q * 8 + hi * 4;
          u16x4 o = {f2bf(acc[mi][ni][q * 4 + 0]), f2bf(acc[mi][ni][q * 4 + 1]),
                     f2bf(acc[mi][ni][q * 4 + 2]), f2bf(acc[mi][ni][q * 4 + 3])};
          *(u16x4*)&vt[(size_t)vcl * 1024 + t0] = o;
        }
      }
  }
}

// ---------------------------------------------------------------------------
// 128x64-tile bf16 GEMM (final Wo), 2-phase double-buffered. Grid 1-D (256),
// m-major XCD chunks: each XCD owns 2 A-panels + all 16 B-panels (~2.5 MB).
// ---------------------------------------------------------------------------
__global__ __launch_bounds__(256) void gemmWo(const u16* __restrict__ A,
                                              const u16* __restrict__ Bt,
                                              float* __restrict__ C,
                                              int M, int N, int K) {
  __shared__ u16 Asm[2][8192];   // 2 x (128 x 64)
  __shared__ u16 Bsm[2][4096];   // 2 x (64 x 64)
  int tid = threadIdx.x, w = tid >> 6, l = tid & 63;
  int bid = blockIdx.x;
  int swz = (bid & 7) * 32 + (bid >> 3);   // 256 % 8 == 0 -> bijective
  int mt = swz >> 4, ntile = swz & 15;     // m-major: 16 n-tiles per m
  int bm = mt << 7, bn = ntile << 6;

  int srow = (w << 3) + (l >> 3);
  int schunk = ((l & 7) ^ (l >> 3)) << 3;
  const u16* pA = A  + (size_t)(bm + srow) * K + schunk;
  const u16* pB = Bt + (size_t)(bn + srow) * K + schunk;
  char* AsmB = (char*)Asm;
  char* BsmB = (char*)Bsm;
  int ldsw = w << 10;
  int l31 = l & 31, hi = l >> 5;

  int nt = K >> 6;
#pragma unroll
  for (int i = 0; i < 4; ++i)
    gll16(pA + (size_t)(i * 32) * K, AsmB + i * 4096 + ldsw);
#pragma unroll
  for (int i = 0; i < 2; ++i)
    gll16(pB + (size_t)(i * 32) * K, BsmB + i * 4096 + ldsw);
  __syncthreads();

  f32x16 acc[2] = {};
  int cur = 0;
  for (int t = 0; t < nt; ++t) {
    if (t + 1 < nt) {
      int k0 = (t + 1) << 6;
#pragma unroll
      for (int i = 0; i < 4; ++i)
        gll16(pA + (size_t)(i * 32) * K + k0, AsmB + ((cur ^ 1) << 14) + i * 4096 + ldsw);
#pragma unroll
      for (int i = 0; i < 2; ++i)
        gll16(pB + (size_t)(i * 32) * K + k0, BsmB + ((cur ^ 1) << 13) + i * 4096 + ldsw);
    }
    const u16* Ac = Asm[cur];
    const u16* Bc = Bsm[cur];
    bf16x8 a[4], b[2][4];
#pragma unroll
    for (int ks = 0; ks < 4; ++ks) {
      int ar = w * 32 + l31;
      a[ks] = *(const bf16x8*)(Ac + ar * 64 + ((((ks << 1) + hi) ^ (ar & 7)) << 3));
#pragma unroll
      for (int ni = 0; ni < 2; ++ni) {
        int br = ni * 32 + l31;
        b[ni][ks] = *(const bf16x8*)(Bc + br * 64 + ((((ks << 1) + hi) ^ (br & 7)) << 3));
      }
    }
#pragma unroll
    for (int ks = 0; ks < 4; ++ks)
#pragma unroll
      for (int ni = 0; ni < 2; ++ni)
        acc[ni] = __builtin_amdgcn_mfma_f32_32x32x16_bf16(a[ks], b[ni][ks], acc[ni], 0, 0, 0);
    __syncthreads();
    cur ^= 1;
  }
#pragma unroll
  for (int ni = 0; ni < 2; ++ni) {
    int colg = bn + ni * 32 + l31;
#pragma unroll
    for (int q = 0; q < 4; ++q) {
      int row0 = bm + w * 32 + q * 8 + hi * 4;
#pragma unroll
      for (int j = 0; j < 4; ++j)
        C[(size_t)(row0 + j) * N + colg] = acc[ni][q * 4 + j];
    }
  }
}

// ---------------------------------------------------------------------------
// Fused misc prep: z=0..3 weight transposes into fused WallTb, z=4 Wo->Wotb,
// z=5 x->bf16, z=6 Wgk1^T zero-padded into WallTb rows 3072..3199.
// Transposes use float4 loads + u16x4 stores (vectorized both sides).
// ---------------------------------------------------------------------------
__global__ __launch_bounds__(256) void prep_misc(const float* __restrict__ x,
                                                 const float* __restrict__ Wq,
                                                 const float* __restrict__ Wk,
                                                 const float* __restrict__ Wv,
                                                 const float* __restrict__ Wg,
                                                 const float* __restrict__ Wo,
                                                 const float* __restrict__ Wgk1,
                                                 u16* __restrict__ xbb,
                                                 u16* __restrict__ WallTb,
                                                 u16* __restrict__ Wotb) {
  int z = blockIdx.z;
  int tid = threadIdx.x;
  if (z == 5) {
    size_t i0 = ((size_t)(blockIdx.y * 32 + blockIdx.x)) * 2048 + tid * 4;
    float4 v0 = *(const float4*)&x[i0];
    float4 v1 = *(const float4*)&x[i0 + 1024];
    u16x4 o0 = {f2bf(v0.x), f2bf(v0.y), f2bf(v0.z), f2bf(v0.w)};
    u16x4 o1 = {f2bf(v1.x), f2bf(v1.y), f2bf(v1.z), f2bf(v1.w)};
    *(u16x4*)&xbb[i0] = o0;
    *(u16x4*)&xbb[i0 + 1024] = o1;
    return;
  }
  if (z == 6) {
    if (blockIdx.x != 0) return;
    int col = blockIdx.y * 32 + (tid & 31);
#pragma unroll
    for (int i = 0; i < 16; ++i) {
      int rr = (tid >> 5) + i * 8;   // 0..127
      float v = (rr < LR_) ? Wgk1[(size_t)col * LR_ + rr] : 0.f;
      WallTb[(size_t)(3072 + rr) * 1024 + col] = f2bf(v);
    }
    return;
  }
  const float* in; u16* outp; int C;
  if (z == 0)      { in = Wq; outp = WallTb;               C = 512; }
  else if (z == 1) { in = Wk; outp = WallTb + 512 * 1024;  C = 512; }
  else if (z == 2) { in = Wv; outp = WallTb + 1024 * 1024; C = 1024; }
  else if (z == 3) { in = Wg; outp = WallTb + 2048 * 1024; C = 1024; }
  else             { in = Wo; outp = Wotb;                 C = 1024; }
  int bx = blockIdx.x << 5, by = blockIdx.y << 5;
  if (bx >= C) return;
  __shared__ float tile[32][33];
  // load: 32x32 f32 tile, float4 per thread (256 thr x 4 = 1024 elems)
  {
    int lr = tid >> 3, lc4 = (tid & 7) << 2;
    float4 v = *(const float4*)&in[(size_t)(by + lr) * C + bx + lc4];
    tile[lr][lc4 + 0] = v.x;
    tile[lr][lc4 + 1] = v.y;
    tile[lr][lc4 + 2] = v.z;
    tile[lr][lc4 + 3] = v.w;
  }
  __syncthreads();
  // store transposed: out[bx+sc][by+sr] = bf16(tile[sr][sc]), u16x4 per thread
  {
    int sc = tid >> 3, sr4 = (tid & 7) << 2;
    u16x4 o = {f2bf(tile[sr4 + 0][sc]), f2bf(tile[sr4 + 1][sc]),
               f2bf(tile[sr4 + 2][sc]), f2bf(tile[sr4 + 3][sc])};
    *(u16x4*)&outp[(size_t)(bx + sc) * 1024 + by + sr4] = o;
  }
}

// ---------------------------------------------------------------------------
// prep2: gate (xg1@Wgk2+b -> logsigmoid/16 -> prefix), bf16 Q~/Kinv/KdecT, D.
// grid 256 = (unit 0..127) x (j-half jh). u16x4-vectorized global traffic.
// ---------------------------------------------------------------------------
__global__ __launch_bounds__(256) void prep2(const float* __restrict__ Wgk2,
                                             const float* __restrict__ bgk2,
                                             const u16* __restrict__ Pb,
                                             u16* __restrict__ qtb,
                                             u16* __restrict__ kinvb,
                                             u16* __restrict__ kdecTb,
                                             float* __restrict__ D) {
  __shared__ float gc[64][65];
  __shared__ u16 kbuf[64][65];
  __shared__ float xs[64][17];
  int bx = blockIdx.x;
  int unit = bx >> 1, jh = bx & 1;
  int c = unit & 15, bh = unit >> 4;
  int b = bh >> 2, h = bh & 3;
  int tid = threadIdx.x;
  int brow = b * T_ + c * CHUNK;
  size_t gbase = (size_t)brow * 512 + h * 128 + jh * 64;

  // xs load: 64 rows x 16 cols, u16x4 per thread
  {
    int i = tid >> 2, r4 = (tid & 3) << 2;
    u16x4 xv = *(const u16x4*)&Pb[(size_t)(brow + i) * PN + 3072 + r4];
#pragma unroll
    for (int k = 0; k < 4; ++k) xs[i][r4 + k] = bf2f(xv[k]);
  }
  __syncthreads();
  {
    int j = tid & 63, i0 = tid >> 6;
    int n = h * 128 + jh * 64 + j;
    float w2[LR_];
#pragma unroll
    for (int r = 0; r < LR_; ++r) w2[r] = Wgk2[r * DK_ + n];
    float bb = bgk2[n];
#pragma unroll 4
    for (int e = 0; e < 16; ++e) {
      int i = e * 4 + i0;
      float sv = bb;
#pragma unroll
      for (int r = 0; r < LR_; ++r) sv = fmaf(xs[i][r], w2[r], sv);
      float ls = fminf(sv, 0.f) - log1pf(__expf(-fabsf(sv)));
      gc[i][j] = ls * (1.0f / 16.0f);
    }
  }
  __syncthreads();
  if (tid < 64) {
    float g = 0.f;
    for (int i = 0; i < 64; ++i) { g += gc[i][tid]; gc[i][tid] = g; }
    D[unit * 128 + jh * 64 + tid] = __expf(g);
  }
  __syncthreads();

  const float scale = 0.08838834764831845f;
  const u16* Pq = Pb + (size_t)brow * PN + h * 128 + jh * 64;
  const u16* Pk = Pq + 512;
  // pass 2: 64x64, u16x4 per thread per iter (4 iters)
#pragma unroll
  for (int e = 0; e < 4; ++e) {
    int idx = e * 256 + tid;
    int i = idx >> 4, j4 = (idx & 15) << 2;
    u16x4 qv4 = *(const u16x4*)&Pq[(size_t)i * PN + j4];
    u16x4 kv4 = *(const u16x4*)&Pk[(size_t)i * PN + j4];
    u16x4 qo, ko;
#pragma unroll
    for (int k = 0; k < 4; ++k) {
      int j = j4 + k;
      float gv = gc[i][j];
      kbuf[i][j] = kv4[k];
      qo[k] = f2bf(bf2f(qv4[k]) * __expf(gv) * scale);
      ko[k] = f2bf(bf2f(kv4[k]) * __expf(-gv));
    }
    *(u16x4*)&qtb[gbase + (size_t)i * 512 + j4]   = qo;
    *(u16x4*)&kinvb[gbase + (size_t)i * 512 + j4] = ko;
  }
  __syncthreads();
  u16* kd = kdecTb + (size_t)unit * 8192 + (size_t)(jh * 64) * 64;
  // pass 3: kd[j][i] transposed write, u16x4 per thread per iter
#pragma unroll
  for (int e = 0; e < 4; ++e) {
    int idx = e * 256 + tid;
    int j = idx >> 4, i4 = (idx & 15) << 2;
    float G = gc[63][j];
    u16x4 o;
#pragma unroll
    for (int k = 0; k < 4; ++k) {
      float kv = bf2f(kbuf[i4 + k][j]);
      float gv = gc[i4 + k][j];
      o[k] = f2bf(kv * __expf(G - gv));
    }
    *(u16x4*)&kd[(size_t)j * 64 + i4] = o;
  }
}

// ---------------------------------------------------------------------------
// state_combine: per (kh, vs, bh) block, V^T slice resident in LDS; for each
// chunk c: U = KdecT@V (MFMA, KdecT double-buffered), S = D*S + U in regs,
// StT[c+1] written bf16. Slot 0 zeroed. grid (2, 16, 8).
// ---------------------------------------------------------------------------
__global__ __launch_bounds__(256) void state_combine(const u16* __restrict__ Vtb,
                                                     const u16* __restrict__ kdecTb,
                                                     const float* __restrict__ D,
                                                     u16* __restrict__ StT) {
  __shared__ u16 VtS[16384];    // 16 v-rows x 1024 t (chunk-swizzled)
  __shared__ u16 Kdb[2][4096];  // 64 k-rows x 64 t, double-buffered
  int kh = blockIdx.x, vs = blockIdx.y, bh = blockIdx.z;
  int tid = threadIdx.x, w = tid >> 6, l = tid & 63;
  int lrow = l & 15, g4 = l >> 4;
  int unit0 = bh * 16;

  {
    const u16* base = Vtb + (size_t)bh * 262144 + (size_t)(vs * 16) * 1024;
#pragma unroll
    for (int i = 0; i < 8; ++i) {
      int slin = i * 256 + w * 64 + l;
      int row = slin >> 7, chd = slin & 127;
      gll16(base + (size_t)row * 1024 + ((chd ^ (row & 7)) << 3),
            (char*)VtS + i * 4096 + (w << 10));
    }
  }
  int vc = vs * 16 + lrow;
  int kd0 = kh * 64 + w * 16 + (g4 << 2);
  {
    u16x4 z = {0, 0, 0, 0};
    *(u16x4*)&StT[(size_t)bh * 32768 + (size_t)vc * 128 + kd0] = z;
  }
  {
    const u16* kb = kdecTb + (size_t)unit0 * 8192 + (size_t)(kh * 64) * 64;
#pragma unroll
    for (int i = 0; i < 2; ++i) {
      int slin = i * 256 + w * 64 + l;
      int row = slin >> 3, chd = slin & 7;
      gll16(kb + (size_t)row * 64 + ((chd ^ (row & 7)) << 3),
            (char*)Kdb[0] + i * 4096 + (w << 10));
    }
  }
  f32x4 S = {};
  int cur = 0;
  for (int c = 0; c < 15; ++c) {
    __syncthreads();
    if (c < 14) {
      const u16* kb = kdecTb + (size_t)(unit0 + c + 1) * 8192 + (size_t)(kh * 64) * 64;
#pragma unroll
      for (int i = 0; i < 2; ++i) {
        int slin = i * 256 + w * 64 + l;
        int row = slin >> 3, chd = slin & 7;
        gll16(kb + (size_t)row * 64 + ((chd ^ (row & 7)) << 3),
              (char*)Kdb[cur ^ 1] + i * 4096 + (w << 10));
      }
    }
    const u16* Kc = Kdb[cur];
    f32x4 acc = {};
#pragma unroll
    for (int ks = 0; ks < 2; ++ks) {
      int cidx = c * 8 + ks * 4 + g4;
      bf16x8 bv = *(const bf16x8*)(VtS + lrow * 1024 + ((cidx ^ (lrow & 7)) << 3));
      int row = w * 16 + lrow;
      bf16x8 av = *(const bf16x8*)(Kc + row * 64 + ((((ks << 2) + g4) ^ (row & 7)) << 3));
      acc = __builtin_amdgcn_mfma_f32_16x16x32_bf16(av, bv, acc, 0, 0, 0);
    }
    float4 dv = *(const float4*)&D[(size_t)(unit0 + c) * 128 + kd0];
    S[0] = fmaf(dv.x, S[0], acc[0]);
    S[1] = fmaf(dv.y, S[1], acc[1]);
    S[2] = fmaf(dv.z, S[2], acc[2]);
    S[3] = fmaf(dv.w, S[3], acc[3]);
    u16x4 o = {f2bf(S[0]), f2bf(S[1]), f2bf(S[2]), f2bf(S[3])};
    *(u16x4*)&StT[((size_t)(c + 1) * 8 + bh) * 32768 + (size_t)vc * 128 + kd0] = o;
    cur ^= 1;
  }
}

// ---------------------------------------------------------------------------
// Fused per-half-unit: A = mask(Q~ Kinv^T); O = A V + Q~ S; RMSNorm*gw*swish.
// grid 256 = (unit) x (row-half s). 32 rows x 256 v-cols per block.
// ---------------------------------------------------------------------------
__global__ __launch_bounds__(256) void fused_out(const u16* __restrict__ qtb,
                                                 const u16* __restrict__ kinvb,
                                                 const u16* __restrict__ Vtb,
                                                 const u16* __restrict__ StTb,
                                                 const u16* __restrict__ Pb,
                                                 const float* __restrict__ gw,
                                                 u16* __restrict__ onb) {
  __shared__ u16 Qs[4096];
  __shared__ u16 As[2048];
  __shared__ float rsum[32][4];
  int bx = blockIdx.x;
  int unit = bx >> 1, s = bx & 1;
  int c = unit & 15, bh = unit >> 4;
  int b = bh >> 2, h = bh & 3;
  int tid = threadIdx.x, w = tid >> 6, l = tid & 63;
  int lrow = l & 15, g4 = l >> 4, lx = l & 7;
  int crow = b * T_ + c * CHUNK;
  int brow = crow + s * 32;

  {
    int r0 = tid >> 4;
    int csrc = ((tid & 15) ^ (r0 & 7)) << 3;
    const u16* src = qtb + (size_t)(brow + r0) * 512 + h * 128 + csrc;
    gll16(src, (char*)Qs + (w << 10));
    gll16(src + 16 * 512, (char*)Qs + 4096 + (w << 10));
  }
  const u16* Kbase = kinvb + (size_t)crow * 512 + h * 128;
  int wc1 = w & 1, fr = w >> 1;
  bf16x8 bk[2][4];
#pragma unroll
  for (int nj = 0; nj < 2; ++nj)
#pragma unroll
    for (int ks = 0; ks < 4; ++ks)
      bk[nj][ks] = *(const bf16x8*)(Kbase + (size_t)(wc1 * 32 + nj * 16 + lrow) * 512 + ks * 32 + (g4 << 3));
  __syncthreads();

  f32x4 accA[2] = {};
#pragma unroll
  for (int ks = 0; ks < 4; ++ks) {
    int arow = fr * 16 + lrow;
    bf16x8 aq = *(const bf16x8*)(Qs + arow * 128 + ((((ks << 2) + g4) ^ lx) << 3));
#pragma unroll
    for (int nj = 0; nj < 2; ++nj)
      accA[nj] = __builtin_amdgcn_mfma_f32_16x16x32_bf16(aq, bk[nj][ks], accA[nj], 0, 0, 0);
  }
#pragma unroll
  for (int nj = 0; nj < 2; ++nj)
#pragma unroll
    for (int j = 0; j < 4; ++j) {
      int rg = fr * 16 + (g4 << 2) + j;
      int col = wc1 * 32 + nj * 16 + lrow;
      float vv = (col <= s * 32 + rg) ? accA[nj][j] : 0.f;
      int chunk = (col >> 3) ^ (rg & 7);
      As[rg * 64 + (chunk << 3) + (lrow & 7)] = f2bf(vv);
    }
  __syncthreads();

  f32x4 acc[2][4] = {};
  const u16* Vbase = Vtb + (size_t)bh * 262144 + (size_t)(w * 64) * 1024 + c * 64;
  const u16* Sbase = StTb + (((size_t)(c * 8 + bh)) * 256 + w * 64) * 128;
#pragma unroll
  for (int ks2 = 0; ks2 < 2; ++ks2) {
    bf16x8 bv[4];
#pragma unroll
    for (int nj = 0; nj < 4; ++nj)
      bv[nj] = *(const bf16x8*)(Vbase + (size_t)(nj * 16 + lrow) * 1024 + ks2 * 32 + (g4 << 3));
#pragma unroll
    for (int mi = 0; mi < 2; ++mi) {
      int row = mi * 16 + lrow;
      bf16x8 aa = *(const bf16x8*)(As + row * 64 + ((((ks2 << 2) + g4) ^ lx) << 3));
#pragma unroll
      for (int nj = 0; nj < 4; ++nj)
        acc[mi][nj] = __builtin_amdgcn_mfma_f32_16x16x32_bf16(aa, bv[nj], acc[mi][nj], 0, 0, 0);
    }
  }
#pragma unroll
  for (int ks = 0; ks < 4; ++ks) {
    bf16x8 bs[4];
#pragma unroll
    for (int nj = 0; nj < 4; ++nj)
      bs[nj] = *(const bf16x8*)(Sbase + (size_t)(nj * 16 + lrow) * 128 + ks * 32 + (g4 << 3));
#pragma unroll
    for (int mi = 0; mi < 2; ++mi) {
      int row = mi * 16 + lrow;
      bf16x8 aq = *(const bf16x8*)(Qs + row * 128 + ((((ks << 2) + g4) ^ lx) << 3));
#pragma unroll
      for (int nj = 0; nj < 4; ++nj)
        acc[mi][nj] = __builtin_amdgcn_mfma_f32_16x16x32_bf16(aq, bs[nj], acc[mi][nj], 0, 0, 0);
    }
  }

#pragma unroll
  for (int mi = 0; mi < 2; ++mi)
#pragma unroll
    for (int j = 0; j < 4; ++j) {
      float ss = 0.f;
#pragma unroll
      for (int nj = 0; nj < 4; ++nj) { float o = acc[mi][nj][j]; ss = fmaf(o, o, ss); }
      ss += __shfl_xor(ss, 1);
      ss += __shfl_xor(ss, 2);
      ss += __shfl_xor(ss, 4);
      ss += __shfl_xor(ss, 8);
      if (lrow == 0) rsum[mi * 16 + (g4 << 2) + j][w] = ss;
    }
  __syncthreads();
  const u16* Gbase = Pb + (size_t)brow * PN + 2048 + h * 256;
#pragma unroll
  for (int mi = 0; mi < 2; ++mi)
#pragma unroll
    for (int j = 0; j < 4; ++j) {
      int row = mi * 16 + (g4 << 2) + j;
      float4 rs = *(float4*)&rsum[row][0];
      float rn = rsqrtf((rs.x + rs.y + rs.z + rs.w) * (1.f / 256.f) + 1e-5f);
#pragma unroll
      for (int nj = 0; nj < 4; ++nj) {
        int vc = w * 64 + nj * 16 + lrow;
        float o = acc[mi][nj][j] * rn * gw[vc];
        float gval = bf2f(Gbase[(size_t)row * PN + vc]);
        float sw = gval / (1.f + __expf(-gval));
        onb[(size_t)(brow + row) * 1024 + h * 256 + vc] = f2bf(o * sw);
      }
    }
}

// ---------------------------------------------------------------------------
extern "C" void kernel_launch(void* const* d_in, const int* in_sizes, int n_in,
                              void* d_out, int out_size, void* d_ws, size_t ws_size,
                              hipStream_t stream) {
  const float* x    = (const float*)d_in[0];
  const float* Wq   = (const float*)d_in[1];
  const float* Wk   = (const float*)d_in[2];
  const float* Wv   = (const float*)d_in[3];
  const float* Wgk1 = (const float*)d_in[4];
  const float* Wgk2 = (const float*)d_in[5];
  const float* bgk2 = (const float*)d_in[6];
  const float* Wg   = (const float*)d_in[7];
  const float* Wo   = (const float*)d_in[8];
  const float* gw   = (const float*)d_in[9];
  float* out = (float*)d_out;

  float* F = (float*)d_ws;
  u16*   Pb     = (u16*)F;                       // [2048][3200] bf16
  u16*   WallTb = (u16*)(F + 3276800);           // [3200][1024] bf16 -> kdecT+onb
  u16*   Wotb   = (u16*)(F + 4915200);           // [1024][1024] bf16
  u16*   xbb    = (u16*)(F + 5439488);           // x bf16 -> qtb+kinvb
  u16*   Vtb    = (u16*)(F + 6488064);           // [8][256][1024] bf16
  float* D      = F + 7536640;                   // [128][128] f32
  u16*   StT    = (u16*)(F + 7553024);           // [16][8][32768] bf16

  u16* qtb    = xbb;                             // aliases (xbb dead after proj)
  u16* kinvb  = xbb + 1048576;
  u16* kdecTb = WallTb;                          // WallTb dead after proj
  u16* onb    = WallTb + 1048576;

  dim3 blk(256);
  prep_misc<<<dim3(32, 32, 7), blk, 0, stream>>>(x, Wq, Wk, Wv, Wg, Wo, Wgk1,
                                                 xbb, WallTb, Wotb);
  // 400 tiles (25 n x 16 m), n-major, 50 tiles per XCD chunk
  gemm128<true, true><<<dim3(400), blk, 0, stream>>>(xbb, WallTb, Pb, Vtb,
                                                     2048, PN, H_, 16, 50);
  prep2<<<256, blk, 0, stream>>>(Wgk2, bgk2, Pb, qtb, kinvb, kdecTb, D);
  state_combine<<<dim3(2, 16, 8), blk, 0, stream>>>(Vtb, kdecTb, D, StT);
  fused_out<<<256, blk, 0, stream>>>(qtb, kinvb, Vtb, StT, Pb, gw, onb);
  gemmWo<<<dim3(256), blk, 0, stream>>>(onb, Wotb, out, 2048, H_, DV_);
}

// Round 13
// 90.375 us; speedup vs baseline: 1.3226x; 1.0212x over previous
//
#include <hip/hip_runtime.h>
#include <math.h>

#define T_  1024
#define H_  1024
#define DK_ 512
#define DV_ 1024
#define LR_ 16
#define CHUNK 64
#define PN  3200   // fused projection width: q(512)|k(512)|v(1024)|g(1024)|xg1pad(128)

using f32x4  = __attribute__((ext_vector_type(4))) float;
using f32x16 = __attribute__((ext_vector_type(16))) float;
using bf16x8 = __attribute__((ext_vector_type(8))) short;
using u16x4  = __attribute__((ext_vector_type(4))) unsigned short;
typedef unsigned short u16;

__device__ __forceinline__ u16 f2bf(float f) {
  union { float f; unsigned int u; } v; v.f = f;
  unsigned int r = v.u + 0x7FFF + ((v.u >> 16) & 1);
  return (u16)(r >> 16);
}
__device__ __forceinline__ float bf2f(u16 u) {
  union { unsigned int i; float f; } v; v.i = ((unsigned int)u) << 16;
  return v.f;
}
__device__ __forceinline__ void gll16(const void* g, void* l) {
  __builtin_amdgcn_global_load_lds((const __attribute__((address_space(1))) void*)g,
                                   (__attribute__((address_space(3))) void*)l, 16, 0, 0);
}

// ---------------------------------------------------------------------------
// 128x128-tile bf16 GEMM via mfma_f32_32x32x16, 2-phase double-buffered LDS.
// C[M,N] = A[M,K] @ Bt[N,K]. BK=64, 4 waves, wave = 2x2 of 32x32 frags.
// 1-D grid, n-major XCD-chunk swizzle (bijective, grid%8==0).
// VT: blocks in the V column range emit ONLY the transposed tile to Vtb
// (Pb's v-columns are never read downstream — skip the C store).
// ---------------------------------------------------------------------------
template <bool OBF, bool VT>
__global__ __launch_bounds__(256) void gemm128(const u16* __restrict__ A,
                                               const u16* __restrict__ Bt,
                                               void* __restrict__ Cv,
                                               u16* __restrict__ Vtb,
                                               int M, int N, int K,
                                               int ntile_m, int chunk) {
  __shared__ u16 Asm[2][8192];   // 2 x (128 x 64)
  __shared__ u16 Bsm[2][8192];
  int tid = threadIdx.x, w = tid >> 6, l = tid & 63;
  int bid = blockIdx.x;
  int swz = (bid & 7) * chunk + (bid >> 3);
  int nt = swz / ntile_m, mt = swz - nt * ntile_m;
  int bm = mt << 7, bn = nt << 7;

  int srow = (w << 3) + (l >> 3);
  int schunk = ((l & 7) ^ (l >> 3)) << 3;
  const u16* pA = A  + (size_t)(bm + srow) * K + schunk;
  const u16* pB = Bt + (size_t)(bn + srow) * K + schunk;
  char* AsmB = (char*)Asm;
  char* BsmB = (char*)Bsm;
  int ldsw = w << 10;

  int wr = w >> 1, wc = w & 1;
  int l31 = l & 31, hi = l >> 5;

  int nt_k = K >> 6;
#pragma unroll
  for (int i = 0; i < 4; ++i) {
    gll16(pA + (size_t)(i * 32) * K, AsmB + i * 4096 + ldsw);
    gll16(pB + (size_t)(i * 32) * K, BsmB + i * 4096 + ldsw);
  }
  __syncthreads();

  f32x16 acc[2][2] = {};
  int cur = 0;
  for (int t = 0; t < nt_k; ++t) {
    if (t + 1 < nt_k) {           // issue next-tile loads into the other buffer
      int k0 = (t + 1) << 6;
      int off = (cur ^ 1) << 14;
#pragma unroll
      for (int i = 0; i < 4; ++i) {
        gll16(pA + (size_t)(i * 32) * K + k0, AsmB + off + i * 4096 + ldsw);
        gll16(pB + (size_t)(i * 32) * K + k0, BsmB + off + i * 4096 + ldsw);
      }
    }
    const u16* Ac = Asm[cur];
    const u16* Bc = Bsm[cur];
    bf16x8 a[2][4], b[2][4];
#pragma unroll
    for (int mi = 0; mi < 2; ++mi)
#pragma unroll
      for (int ks = 0; ks < 4; ++ks) {
        int ar = wr * 64 + mi * 32 + l31;
        int br = wc * 64 + mi * 32 + l31;
        a[mi][ks] = *(const bf16x8*)(Ac + ar * 64 + ((((ks << 1) + hi) ^ (ar & 7)) << 3));
        b[mi][ks] = *(const bf16x8*)(Bc + br * 64 + ((((ks << 1) + hi) ^ (br & 7)) << 3));
      }
#pragma unroll
    for (int ks = 0; ks < 4; ++ks)
#pragma unroll
      for (int mi = 0; mi < 2; ++mi)
#pragma unroll
        for (int ni = 0; ni < 2; ++ni)
          acc[mi][ni] = __builtin_amdgcn_mfma_f32_32x32x16_bf16(
              a[mi][ks], b[ni][ks], acc[mi][ni], 0, 0, 0);
    __syncthreads();
    cur ^= 1;
  }
  bool vtile = VT && bn >= 1024 && bn < 2048;
  // C/D: col = l&31, row = (reg&3) + 8*(reg>>2) + 4*(l>>5)
  if (!vtile) {
#pragma unroll
    for (int mi = 0; mi < 2; ++mi)
#pragma unroll
      for (int ni = 0; ni < 2; ++ni) {
        int colg = bn + wc * 64 + ni * 32 + l31;
#pragma unroll
        for (int q = 0; q < 4; ++q) {
          int row0 = bm + wr * 64 + mi * 32 + q * 8 + hi * 4;
#pragma unroll
          for (int j = 0; j < 4; ++j) {
            float vv = acc[mi][ni][q * 4 + j];
            if (OBF) ((u16*)Cv)[(size_t)(row0 + j) * N + colg] = f2bf(vv);
            else     ((float*)Cv)[(size_t)(row0 + j) * N + colg] = vv;
          }
        }
      }
  } else {                         // emit only V^T for this tile
    int h = (bn - 1024) >> 8;
    int bb_ = bm >> 10;
    u16* vt = Vtb + (size_t)(bb_ * 4 + h) * 262144;
    int tbase = bm & 1023;
#pragma unroll
    for (int mi = 0; mi < 2; ++mi)
#pragma unroll
      for (int ni = 0; ni < 2; ++ni) {
        int vcl = ((bn - 1024) & 255) + wc * 64 + ni * 32 + l31;
#pragma unroll
        for (int q = 0; q < 4; ++q) {
          int t0 = tbase + wr * 64 + mi * 32 + q * 8 + hi * 4;
          u16x4 o = {f2bf(acc[mi][ni][q * 4 + 0]), f2bf(acc[mi][ni][q * 4 + 1]),
                     f2bf(acc[mi][ni][q * 4 + 2]), f2bf(acc[mi][ni][q * 4 + 3])};
          *(u16x4*)&vt[(size_t)vcl * 1024 + t0] = o;
        }
      }
  }
}

// ---------------------------------------------------------------------------
// 128x64-tile bf16 GEMM (final Wo), 2-phase double-buffered. Grid 1-D (256),
// m-major XCD chunks.
// ---------------------------------------------------------------------------
__global__ __launch_bounds__(256) void gemmWo(const u16* __restrict__ A,
                                              const u16* __restrict__ Bt,
                                              float* __restrict__ C,
                                              int M, int N, int K) {
  __shared__ u16 Asm[2][8192];   // 2 x (128 x 64)
  __shared__ u16 Bsm[2][4096];   // 2 x (64 x 64)
  int tid = threadIdx.x, w = tid >> 6, l = tid & 63;
  int bid = blockIdx.x;
  int swz = (bid & 7) * 32 + (bid >> 3);   // 256 % 8 == 0 -> bijective
  int mt = swz >> 4, ntile = swz & 15;     // m-major: 16 n-tiles per m
  int bm = mt << 7, bn = ntile << 6;

  int srow = (w << 3) + (l >> 3);
  int schunk = ((l & 7) ^ (l >> 3)) << 3;
  const u16* pA = A  + (size_t)(bm + srow) * K + schunk;
  const u16* pB = Bt + (size_t)(bn + srow) * K + schunk;
  char* AsmB = (char*)Asm;
  char* BsmB = (char*)Bsm;
  int ldsw = w << 10;
  int l31 = l & 31, hi = l >> 5;

  int nt = K >> 6;
#pragma unroll
  for (int i = 0; i < 4; ++i)
    gll16(pA + (size_t)(i * 32) * K, AsmB + i * 4096 + ldsw);
#pragma unroll
  for (int i = 0; i < 2; ++i)
    gll16(pB + (size_t)(i * 32) * K, BsmB + i * 4096 + ldsw);
  __syncthreads();

  f32x16 acc[2] = {};
  int cur = 0;
  for (int t = 0; t < nt; ++t) {
    if (t + 1 < nt) {
      int k0 = (t + 1) << 6;
#pragma unroll
      for (int i = 0; i < 4; ++i)
        gll16(pA + (size_t)(i * 32) * K + k0, AsmB + ((cur ^ 1) << 14) + i * 4096 + ldsw);
#pragma unroll
      for (int i = 0; i < 2; ++i)
        gll16(pB + (size_t)(i * 32) * K + k0, BsmB + ((cur ^ 1) << 13) + i * 4096 + ldsw);
    }
    const u16* Ac = Asm[cur];
    const u16* Bc = Bsm[cur];
    bf16x8 a[4], b[2][4];
#pragma unroll
    for (int ks = 0; ks < 4; ++ks) {
      int ar = w * 32 + l31;
      a[ks] = *(const bf16x8*)(Ac + ar * 64 + ((((ks << 1) + hi) ^ (ar & 7)) << 3));
#pragma unroll
      for (int ni = 0; ni < 2; ++ni) {
        int br = ni * 32 + l31;
        b[ni][ks] = *(const bf16x8*)(Bc + br * 64 + ((((ks << 1) + hi) ^ (br & 7)) << 3));
      }
    }
#pragma unroll
    for (int ks = 0; ks < 4; ++ks)
#pragma unroll
      for (int ni = 0; ni < 2; ++ni)
        acc[ni] = __builtin_amdgcn_mfma_f32_32x32x16_bf16(a[ks], b[ni][ks], acc[ni], 0, 0, 0);
    __syncthreads();
    cur ^= 1;
  }
#pragma unroll
  for (int ni = 0; ni < 2; ++ni) {
    int colg = bn + ni * 32 + l31;
#pragma unroll
    for (int q = 0; q < 4; ++q) {
      int row0 = bm + w * 32 + q * 8 + hi * 4;
#pragma unroll
      for (int j = 0; j < 4; ++j)
        C[(size_t)(row0 + j) * N + colg] = acc[ni][q * 4 + j];
    }
  }
}

// ---------------------------------------------------------------------------
// Fused misc prep, exact 1-D grid (5152 blocks, no early-return waste):
//   [0,512)      Wq  transpose -> WallTb rows 0..511
//   [512,1024)   Wk  transpose -> WallTb rows 512..1023
//   [1024,2048)  Wv  transpose -> WallTb rows 1024..2047
//   [2048,3072)  Wg  transpose -> WallTb rows 2048..3071
//   [3072,4096)  Wo  transpose -> Wotb
//   [4096,5120)  x -> bf16
//   [5120,5152)  Wgk1^T zero-padded -> WallTb rows 3072..3199
// ---------------------------------------------------------------------------
__global__ __launch_bounds__(256) void prep_misc(const float* __restrict__ x,
                                                 const float* __restrict__ Wq,
                                                 const float* __restrict__ Wk,
                                                 const float* __restrict__ Wv,
                                                 const float* __restrict__ Wg,
                                                 const float* __restrict__ Wo,
                                                 const float* __restrict__ Wgk1,
                                                 u16* __restrict__ xbb,
                                                 u16* __restrict__ WallTb,
                                                 u16* __restrict__ Wotb) {
  int bid = blockIdx.x;
  int tid = threadIdx.x;
  if (bid >= 4096) {
    if (bid >= 5120) {   // Wgk1^T pad
      int col = (bid - 5120) * 32 + (tid & 31);
#pragma unroll
      for (int i = 0; i < 16; ++i) {
        int rr = (tid >> 5) + i * 8;   // 0..127
        float v = (rr < LR_) ? Wgk1[(size_t)col * LR_ + rr] : 0.f;
        WallTb[(size_t)(3072 + rr) * 1024 + col] = f2bf(v);
      }
      return;
    }
    // x -> bf16 (1024 blocks x 2048 elems)
    size_t i0 = ((size_t)(bid - 4096)) * 2048 + tid * 4;
    float4 v0 = *(const float4*)&x[i0];
    float4 v1 = *(const float4*)&x[i0 + 1024];
    u16x4 o0 = {f2bf(v0.x), f2bf(v0.y), f2bf(v0.z), f2bf(v0.w)};
    u16x4 o1 = {f2bf(v1.x), f2bf(v1.y), f2bf(v1.z), f2bf(v1.w)};
    *(u16x4*)&xbb[i0] = o0;
    *(u16x4*)&xbb[i0 + 1024] = o1;
    return;
  }
  const float* in; u16* outp; int C, local;
  if (bid < 512)       { in = Wq; outp = WallTb;               C = 512;  local = bid; }
  else if (bid < 1024) { in = Wk; outp = WallTb + 512 * 1024;  C = 512;  local = bid - 512; }
  else if (bid < 2048) { in = Wv; outp = WallTb + 1024 * 1024; C = 1024; local = bid - 1024; }
  else if (bid < 3072) { in = Wg; outp = WallTb + 2048 * 1024; C = 1024; local = bid - 2048; }
  else                 { in = Wo; outp = Wotb;                 C = 1024; local = bid - 3072; }
  int xt = C >> 5;                       // x-tiles (16 or 32, pow2)
  int bx = (local & (xt - 1)) << 5, by = (local / xt) << 5;
  __shared__ float tile[32][33];
  // load: 32x32 f32 tile, float4 per thread
  {
    int lr = tid >> 3, lc4 = (tid & 7) << 2;
    float4 v = *(const float4*)&in[(size_t)(by + lr) * C + bx + lc4];
    tile[lr][lc4 + 0] = v.x;
    tile[lr][lc4 + 1] = v.y;
    tile[lr][lc4 + 2] = v.z;
    tile[lr][lc4 + 3] = v.w;
  }
  __syncthreads();
  // store transposed: out[bx+sc][by+sr] = bf16(tile[sr][sc]), u16x4 per thread
  {
    int sc = tid >> 3, sr4 = (tid & 7) << 2;
    u16x4 o = {f2bf(tile[sr4 + 0][sc]), f2bf(tile[sr4 + 1][sc]),
               f2bf(tile[sr4 + 2][sc]), f2bf(tile[sr4 + 3][sc])};
    *(u16x4*)&outp[(size_t)(bx + sc) * 1024 + by + sr4] = o;
  }
}

// ---------------------------------------------------------------------------
// prep2: gate (xg1@Wgk2+b -> logsigmoid/16 -> prefix), bf16 Q~/Kinv/KdecT, D.
// grid 256 = (unit 0..127) x (j-half jh). u16x4-vectorized global traffic.
// ---------------------------------------------------------------------------
__global__ __launch_bounds__(256) void prep2(const float* __restrict__ Wgk2,
                                             const float* __restrict__ bgk2,
                                             const u16* __restrict__ Pb,
                                             u16* __restrict__ qtb,
                                             u16* __restrict__ kinvb,
                                             u16* __restrict__ kdecTb,
                                             float* __restrict__ D) {
  __shared__ float gc[64][65];
  __shared__ u16 kbuf[64][65];
  __shared__ float xs[64][17];
  int bx = blockIdx.x;
  int unit = bx >> 1, jh = bx & 1;
  int c = unit & 15, bh = unit >> 4;
  int b = bh >> 2, h = bh & 3;
  int tid = threadIdx.x;
  int brow = b * T_ + c * CHUNK;
  size_t gbase = (size_t)brow * 512 + h * 128 + jh * 64;

  {
    int i = tid >> 2, r4 = (tid & 3) << 2;
    u16x4 xv = *(const u16x4*)&Pb[(size_t)(brow + i) * PN + 3072 + r4];
#pragma unroll
    for (int k = 0; k < 4; ++k) xs[i][r4 + k] = bf2f(xv[k]);
  }
  __syncthreads();
  {
    int j = tid & 63, i0 = tid >> 6;
    int n = h * 128 + jh * 64 + j;
    float w2[LR_];
#pragma unroll
    for (int r = 0; r < LR_; ++r) w2[r] = Wgk2[r * DK_ + n];
    float bb = bgk2[n];
#pragma unroll 4
    for (int e = 0; e < 16; ++e) {
      int i = e * 4 + i0;
      float sv = bb;
#pragma unroll
      for (int r = 0; r < LR_; ++r) sv = fmaf(xs[i][r], w2[r], sv);
      float ls = fminf(sv, 0.f) - log1pf(__expf(-fabsf(sv)));
      gc[i][j] = ls * (1.0f / 16.0f);
    }
  }
  __syncthreads();
  if (tid < 64) {
    float g = 0.f;
    for (int i = 0; i < 64; ++i) { g += gc[i][tid]; gc[i][tid] = g; }
    D[unit * 128 + jh * 64 + tid] = __expf(g);
  }
  __syncthreads();

  const float scale = 0.08838834764831845f;
  const u16* Pq = Pb + (size_t)brow * PN + h * 128 + jh * 64;
  const u16* Pk = Pq + 512;
#pragma unroll
  for (int e = 0; e < 4; ++e) {
    int idx = e * 256 + tid;
    int i = idx >> 4, j4 = (idx & 15) << 2;
    u16x4 qv4 = *(const u16x4*)&Pq[(size_t)i * PN + j4];
    u16x4 kv4 = *(const u16x4*)&Pk[(size_t)i * PN + j4];
    u16x4 qo, ko;
#pragma unroll
    for (int k = 0; k < 4; ++k) {
      int j = j4 + k;
      float gv = gc[i][j];
      kbuf[i][j] = kv4[k];
      qo[k] = f2bf(bf2f(qv4[k]) * __expf(gv) * scale);
      ko[k] = f2bf(bf2f(kv4[k]) * __expf(-gv));
    }
    *(u16x4*)&qtb[gbase + (size_t)i * 512 + j4]   = qo;
    *(u16x4*)&kinvb[gbase + (size_t)i * 512 + j4] = ko;
  }
  __syncthreads();
  u16* kd = kdecTb + (size_t)unit * 8192 + (size_t)(jh * 64) * 64;
#pragma unroll
  for (int e = 0; e < 4; ++e) {
    int idx = e * 256 + tid;
    int j = idx >> 4, i4 = (idx & 15) << 2;
    float G = gc[63][j];
    u16x4 o;
#pragma unroll
    for (int k = 0; k < 4; ++k) {
      float kv = bf2f(kbuf[i4 + k][j]);
      float gv = gc[i4 + k][j];
      o[k] = f2bf(kv * __expf(G - gv));
    }
    *(u16x4*)&kd[(size_t)j * 64 + i4] = o;
  }
}

// ---------------------------------------------------------------------------
// state_combine: per (kh, vs, bh) block, V^T slice resident in LDS; for each
// chunk c: U = KdecT@V (MFMA, KdecT double-buffered), S = D*S + U in regs,
// StT[c+1] written bf16. Slot 0 zeroed. grid (2, 16, 8).
// ---------------------------------------------------------------------------
__global__ __launch_bounds__(256) void state_combine(const u16* __restrict__ Vtb,
                                                     const u16* __restrict__ kdecTb,
                                                     const float* __restrict__ D,
                                                     u16* __restrict__ StT) {
  __shared__ u16 VtS[16384];    // 16 v-rows x 1024 t (chunk-swizzled)
  __shared__ u16 Kdb[2][4096];  // 64 k-rows x 64 t, double-buffered
  int kh = blockIdx.x, vs = blockIdx.y, bh = blockIdx.z;
  int tid = threadIdx.x, w = tid >> 6, l = tid & 63;
  int lrow = l & 15, g4 = l >> 4;
  int unit0 = bh * 16;

  {
    const u16* base = Vtb + (size_t)bh * 262144 + (size_t)(vs * 16) * 1024;
#pragma unroll
    for (int i = 0; i < 8; ++i) {
      int slin = i * 256 + w * 64 + l;
      int row = slin >> 7, chd = slin & 127;
      gll16(base + (size_t)row * 1024 + ((chd ^ (row & 7)) << 3),
            (char*)VtS + i * 4096 + (w << 10));
    }
  }
  int vc = vs * 16 + lrow;
  int kd0 = kh * 64 + w * 16 + (g4 << 2);
  {
    u16x4 z = {0, 0, 0, 0};
    *(u16x4*)&StT[(size_t)bh * 32768 + (size_t)vc * 128 + kd0] = z;
  }
  {
    const u16* kb = kdecTb + (size_t)unit0 * 8192 + (size_t)(kh * 64) * 64;
#pragma unroll
    for (int i = 0; i < 2; ++i) {
      int slin = i * 256 + w * 64 + l;
      int row = slin >> 3, chd = slin & 7;
      gll16(kb + (size_t)row * 64 + ((chd ^ (row & 7)) << 3),
            (char*)Kdb[0] + i * 4096 + (w << 10));
    }
  }
  f32x4 S = {};
  int cur = 0;
  for (int c = 0; c < 15; ++c) {
    __syncthreads();
    if (c < 14) {
      const u16* kb = kdecTb + (size_t)(unit0 + c + 1) * 8192 + (size_t)(kh * 64) * 64;
#pragma unroll
      for (int i = 0; i < 2; ++i) {
        int slin = i * 256 + w * 64 + l;
        int row = slin >> 3, chd = slin & 7;
        gll16(kb + (size_t)row * 64 + ((chd ^ (row & 7)) << 3),
              (char*)Kdb[cur ^ 1] + i * 4096 + (w << 10));
      }
    }
    const u16* Kc = Kdb[cur];
    f32x4 acc = {};
#pragma unroll
    for (int ks = 0; ks < 2; ++ks) {
      int cidx = c * 8 + ks * 4 + g4;
      bf16x8 bv = *(const bf16x8*)(VtS + lrow * 1024 + ((cidx ^ (lrow & 7)) << 3));
      int row = w * 16 + lrow;
      bf16x8 av = *(const bf16x8*)(Kc + row * 64 + ((((ks << 2) + g4) ^ (row & 7)) << 3));
      acc = __builtin_amdgcn_mfma_f32_16x16x32_bf16(av, bv, acc, 0, 0, 0);
    }
    float4 dv = *(const float4*)&D[(size_t)(unit0 + c) * 128 + kd0];
    S[0] = fmaf(dv.x, S[0], acc[0]);
    S[1] = fmaf(dv.y, S[1], acc[1]);
    S[2] = fmaf(dv.z, S[2], acc[2]);
    S[3] = fmaf(dv.w, S[3], acc[3]);
    u16x4 o = {f2bf(S[0]), f2bf(S[1]), f2bf(S[2]), f2bf(S[3])};
    *(u16x4*)&StT[((size_t)(c + 1) * 8 + bh) * 32768 + (size_t)vc * 128 + kd0] = o;
    cur ^= 1;
  }
}

// ---------------------------------------------------------------------------
// Fused per-half-unit: A = mask(Q~ Kinv^T); O = A V + Q~ S; RMSNorm*gw*swish.
// grid 256 = (unit) x (row-half s). 32 rows x 256 v-cols per block.
// ---------------------------------------------------------------------------
__global__ __launch_bounds__(256) void fused_out(const u16* __restrict__ qtb,
                                                 const u16* __restrict__ kinvb,
                                                 const u16* __restrict__ Vtb,
                                                 const u16* __restrict__ StTb,
                                                 const u16* __restrict__ Pb,
                                                 const float* __restrict__ gw,
                                                 u16* __restrict__ onb) {
  __shared__ u16 Qs[4096];
  __shared__ u16 As[2048];
  __shared__ float rsum[32][4];
  int bx = blockIdx.x;
  int unit = bx >> 1, s = bx & 1;
  int c = unit & 15, bh = unit >> 4;
  int b = bh >> 2, h = bh & 3;
  int tid = threadIdx.x, w = tid >> 6, l = tid & 63;
  int lrow = l & 15, g4 = l >> 4, lx = l & 7;
  int crow = b * T_ + c * CHUNK;
  int brow = crow + s * 32;

  {
    int r0 = tid >> 4;
    int csrc = ((tid & 15) ^ (r0 & 7)) << 3;
    const u16* src = qtb + (size_t)(brow + r0) * 512 + h * 128 + csrc;
    gll16(src, (char*)Qs + (w << 10));
    gll16(src + 16 * 512, (char*)Qs + 4096 + (w << 10));
  }
  const u16* Kbase = kinvb + (size_t)crow * 512 + h * 128;
  int wc1 = w & 1, fr = w >> 1;
  bf16x8 bk[2][4];
#pragma unroll
  for (int nj = 0; nj < 2; ++nj)
#pragma unroll
    for (int ks = 0; ks < 4; ++ks)
      bk[nj][ks] = *(const bf16x8*)(Kbase + (size_t)(wc1 * 32 + nj * 16 + lrow) * 512 + ks * 32 + (g4 << 3));
  __syncthreads();

  f32x4 accA[2] = {};
#pragma unroll
  for (int ks = 0; ks < 4; ++ks) {
    int arow = fr * 16 + lrow;
    bf16x8 aq = *(const bf16x8*)(Qs + arow * 128 + ((((ks << 2) + g4) ^ lx) << 3));
#pragma unroll
    for (int nj = 0; nj < 2; ++nj)
      accA[nj] = __builtin_amdgcn_mfma_f32_16x16x32_bf16(aq, bk[nj][ks], accA[nj], 0, 0, 0);
  }
#pragma unroll
  for (int nj = 0; nj < 2; ++nj)
#pragma unroll
    for (int j = 0; j < 4; ++j) {
      int rg = fr * 16 + (g4 << 2) + j;
      int col = wc1 * 32 + nj * 16 + lrow;
      float vv = (col <= s * 32 + rg) ? accA[nj][j] : 0.f;
      int chunk = (col >> 3) ^ (rg & 7);
      As[rg * 64 + (chunk << 3) + (lrow & 7)] = f2bf(vv);
    }
  __syncthreads();

  f32x4 acc[2][4] = {};
  const u16* Vbase = Vtb + (size_t)bh * 262144 + (size_t)(w * 64) * 1024 + c * 64;
  const u16* Sbase = StTb + (((size_t)(c * 8 + bh)) * 256 + w * 64) * 128;
#pragma unroll
  for (int ks2 = 0; ks2 < 2; ++ks2) {
    bf16x8 bv[4];
#pragma unroll
    for (int nj = 0; nj < 4; ++nj)
      bv[nj] = *(const bf16x8*)(Vbase + (size_t)(nj * 16 + lrow) * 1024 + ks2 * 32 + (g4 << 3));
#pragma unroll
    for (int mi = 0; mi < 2; ++mi) {
      int row = mi * 16 + lrow;
      bf16x8 aa = *(const bf16x8*)(As + row * 64 + ((((ks2 << 2) + g4) ^ lx) << 3));
#pragma unroll
      for (int nj = 0; nj < 4; ++nj)
        acc[mi][nj] = __builtin_amdgcn_mfma_f32_16x16x32_bf16(aa, bv[nj], acc[mi][nj], 0, 0, 0);
    }
  }
#pragma unroll
  for (int ks = 0; ks < 4; ++ks) {
    bf16x8 bs[4];
#pragma unroll
    for (int nj = 0; nj < 4; ++nj)
      bs[nj] = *(const bf16x8*)(Sbase + (size_t)(nj * 16 + lrow) * 128 + ks * 32 + (g4 << 3));
#pragma unroll
    for (int mi = 0; mi < 2; ++mi) {
      int row = mi * 16 + lrow;
      bf16x8 aq = *(const bf16x8*)(Qs + row * 128 + ((((ks << 2) + g4) ^ lx) << 3));
#pragma unroll
      for (int nj = 0; nj < 4; ++nj)
        acc[mi][nj] = __builtin_amdgcn_mfma_f32_16x16x32_bf16(aq, bs[nj], acc[mi][nj], 0, 0, 0);
    }
  }

#pragma unroll
  for (int mi = 0; mi < 2; ++mi)
#pragma unroll
    for (int j = 0; j < 4; ++j) {
      float ss = 0.f;
#pragma unroll
      for (int nj = 0; nj < 4; ++nj) { float o = acc[mi][nj][j]; ss = fmaf(o, o, ss); }
      ss += __shfl_xor(ss, 1);
      ss += __shfl_xor(ss, 2);
      ss += __shfl_xor(ss, 4);
      ss += __shfl_xor(ss, 8);
      if (lrow == 0) rsum[mi * 16 + (g4 << 2) + j][w] = ss;
    }
  __syncthreads();
  const u16* Gbase = Pb + (size_t)brow * PN + 2048 + h * 256;
#pragma unroll
  for (int mi = 0; mi < 2; ++mi)
#pragma unroll
    for (int j = 0; j < 4; ++j) {
      int row = mi * 16 + (g4 << 2) + j;
      float4 rs = *(float4*)&rsum[row][0];
      float rn = rsqrtf((rs.x + rs.y + rs.z + rs.w) * (1.f / 256.f) + 1e-5f);
#pragma unroll
      for (int nj = 0; nj < 4; ++nj) {
        int vc = w * 64 + nj * 16 + lrow;
        float o = acc[mi][nj][j] * rn * gw[vc];
        float gval = bf2f(Gbase[(size_t)row * PN + vc]);
        float sw = gval / (1.f + __expf(-gval));
        onb[(size_t)(brow + row) * 1024 + h * 256 + vc] = f2bf(o * sw);
      }
    }
}

// ---------------------------------------------------------------------------
extern "C" void kernel_launch(void* const* d_in, const int* in_sizes, int n_in,
                              void* d_out, int out_size, void* d_ws, size_t ws_size,
                              hipStream_t stream) {
  const float* x    = (const float*)d_in[0];
  const float* Wq   = (const float*)d_in[1];
  const float* Wk   = (const float*)d_in[2];
  const float* Wv   = (const float*)d_in[3];
  const float* Wgk1 = (const float*)d_in[4];
  const float* Wgk2 = (const float*)d_in[5];
  const float* bgk2 = (const float*)d_in[6];
  const float* Wg   = (const float*)d_in[7];
  const float* Wo   = (const float*)d_in[8];
  const float* gw   = (const float*)d_in[9];
  float* out = (float*)d_out;

  float* F = (float*)d_ws;
  u16*   Pb     = (u16*)F;                       // [2048][3200] bf16
  u16*   WallTb = (u16*)(F + 3276800);           // [3200][1024] bf16 -> kdecT+onb
  u16*   Wotb   = (u16*)(F + 4915200);           // [1024][1024] bf16
  u16*   xbb    = (u16*)(F + 5439488);           // x bf16 -> qtb+kinvb
  u16*   Vtb    = (u16*)(F + 6488064);           // [8][256][1024] bf16
  float* D      = F + 7536640;                   // [128][128] f32
  u16*   StT    = (u16*)(F + 7553024);           // [16][8][32768] bf16

  u16* qtb    = xbb;                             // aliases (xbb dead after proj)
  u16* kinvb  = xbb + 1048576;
  u16* kdecTb = WallTb;                          // WallTb dead after proj
  u16* onb    = WallTb + 1048576;

  dim3 blk(256);
  prep_misc<<<5152, blk, 0, stream>>>(x, Wq, Wk, Wv, Wg, Wo, Wgk1,
                                      xbb, WallTb, Wotb);
  // 400 tiles (25 n x 16 m), n-major, 50 tiles per XCD chunk
  gemm128<true, true><<<dim3(400), blk, 0, stream>>>(xbb, WallTb, Pb, Vtb,
                                                     2048, PN, H_, 16, 50);
  prep2<<<256, blk, 0, stream>>>(Wgk2, bgk2, Pb, qtb, kinvb, kdecTb, D);
  state_combine<<<dim3(2, 16, 8), blk, 0, stream>>>(Vtb, kdecTb, D, StT);
  fused_out<<<256, blk, 0, stream>>>(qtb, kinvb, Vtb, StT, Pb, gw, onb);
  gemmWo<<<dim3(256), blk, 0, stream>>>(onb, Wotb, out, 2048, H_, DV_);
}